// Round 1
// 274.415 us; speedup vs baseline: 1.1337x; 1.1337x over previous
//
#include <hip/hip_runtime.h>
#include <stdint.h>

#define N_ANCH   300000
#define N_CLS    80
#define DET_DIM  85
#define TOPK     1000
#define MAXB     300
#define NMS_THR  0.4f
#define CAP      4096
#define NBH      32                              // blocks for the fused select kernel
#define N4       (N_ANCH / 4)
#define ITH      ((N4 + NBH*1024 - 1) / (NBH*1024))

// ws layout (uint32 units) — total 353480 u32 = 1.41 MB (well under prior 2.43 MB use)
#define OFF_SBITS   0          // 300000 u32
#define OFF_HA      300032     // 4096 u32 global hist A (byte %16==0)
#define OFF_HB      304128     // 4096 u32 global hist B (byte %16==0)
#define OFF_META    308224     // 64 u32: [4]=cand cnt [8]=grid barrier
#define OFF_CAND    308288     // 4096 u64 = 8192 u32 (byte %8==0)
#define OFF_TOPK    316480     // 1000 u32
#define OFF_BOXK    317480     // 1000 float4 (byte %16==0)
#define OFF_MASK    321480     // 16000 u64 (byte %8==0)

// ---------------- device-wide barrier (NBH co-resident blocks) ----------------
// Monotone counter: barrier #p waits until counter >= NBH*p. Counter zeroed by
// k_scores each launch (ws is poisoned between launches). Release side:
// __syncthreads drains vmcnt, thread0's __threadfence() writes back L2 (agent
// scope on gfx950 = cross-XCD visible). Acquire side: post-spin __threadfence()
// invalidates L1/L2 so plain loads see other XCDs' data.
__device__ __forceinline__ void gridbar(uint32_t* bar, uint32_t target) {
    __syncthreads();
    if (threadIdx.x == 0) {
        __threadfence();
        __hip_atomic_fetch_add(bar, 1u, __ATOMIC_ACQ_REL, __HIP_MEMORY_SCOPE_AGENT);
        while (__hip_atomic_load(bar, __ATOMIC_RELAXED, __HIP_MEMORY_SCOPE_AGENT) < target)
            __builtin_amdgcn_s_sleep(2);
        __threadfence();
    }
    __syncthreads();
}

// ---------------- scores = max over 80 classes (pure BW pass) ----------------
__global__ __launch_bounds__(256) void k_scores(const float4* __restrict__ cls4,
                                                uint32_t* __restrict__ sbits,
                                                uint32_t* __restrict__ ha,
                                                uint32_t* __restrict__ hb,
                                                uint32_t* __restrict__ meta) {
    int tid = threadIdx.x;
    if (blockIdx.x == 0) {                       // zero state for k_select (ws poisoned)
        if (tid == 0) { meta[4] = 0; meta[8] = 0; }
        for (int i = tid; i < 4096; i += 256) { ha[i] = 0; hb[i] = 0; }
    }
    int wave = tid >> 6, lane = tid & 63, g = lane >> 2, q = lane & 3;
    int row = blockIdx.x * 64 + wave * 16 + g;
    if (row >= N_ANCH) return;
    const float4* rp = cls4 + (size_t)row * 20;  // 80 floats = 20 float4
    float m = -1.0f;
    #pragma unroll
    for (int k = 0; k < 5; k++) {
        float4 v = rp[q + k * 4];
        m = fmaxf(m, fmaxf(fmaxf(v.x, v.y), fmaxf(v.z, v.w)));
    }
    m = fmaxf(m, __shfl_xor(m, 1));
    m = fmaxf(m, __shfl_xor(m, 2));
    if (q == 0) sbits[row] = __float_as_uint(m); // scores >= 0: bit order == value order
}

// ballot-aggregated LDS histogram add (level-A distribution is degenerate:
// ~99.4% of maxes land in one bits[31:20] bin).
__device__ __forceinline__ void agg_add(uint32_t* h, uint32_t bin, bool valid) {
    int lane = threadIdx.x & 63;
    bool done = !valid;
    while (true) {
        unsigned long long rem = __ballot(!done);
        if (rem == 0ull) break;
        int leader = __ffsll((long long)rem) - 1;
        uint32_t lbin = __shfl(bin, leader);
        bool mine = (!done) && (bin == lbin);
        unsigned long long grp = __ballot(mine);
        if (lane == leader) atomicAdd(&h[lbin], (uint32_t)__popcll(grp));
        done = done || mine;
    }
}

// block-wide (1024 thr) threshold find via shfl wave-scan (2 barriers instead of 20):
// given per-thread counts c[k] for bins 4095-(tid*4+k), find bin where the
// descending-suffix count crosses K. res[0]=bin, res[1]=count strictly above.
__device__ __forceinline__ void findthr_core(const uint32_t c[4], uint32_t* wred,
                                             uint32_t K, uint32_t* res) {
    int tid = threadIdx.x, lane = tid & 63, wave = tid >> 6;
    uint32_t s = c[0] + c[1] + c[2] + c[3];
    uint32_t x = s;
    #pragma unroll
    for (int off = 1; off < 64; off <<= 1) {
        uint32_t v = __shfl_up(x, off);
        if (lane >= off) x += v;
    }
    if (lane == 63) wred[wave] = x;
    __syncthreads();
    if (wave == 0) {
        uint32_t w = (lane < 16) ? wred[lane] : 0u;
        #pragma unroll
        for (int off = 1; off < 16; off <<= 1) {
            uint32_t v = __shfl_up(w, off);
            if (lane >= off) w += v;
        }
        if (lane < 16) wred[lane] = w;
    }
    __syncthreads();
    uint32_t base = (wave == 0) ? 0u : wred[wave - 1];
    uint32_t incl = base + x, excl = incl - s;
    if (excl < K && incl >= K) {                 // exactly one thread matches
        uint32_t run = excl;
        #pragma unroll
        for (int k = 0; k < 4; k++) {
            uint32_t nr = run + c[k];
            if (run < K && nr >= K) { res[0] = 4095 - (tid * 4 + k); res[1] = run; }
            run = nr;
        }
    }
    __syncthreads();
}

// ---------------- IoU (fp32, no fma contraction, matches reference op order) ----------------
__device__ __forceinline__ float iou_f(float4 a, float4 b) {
    #pragma clang fp contract(off)
    float areaA = (a.z - a.x) * (a.w - a.y);
    float areaB = (b.z - b.x) * (b.w - b.y);
    float ih = fminf(a.z, b.z) - fmaxf(a.x, b.x); ih = fmaxf(ih, 0.0f);
    float iw = fminf(a.w, b.w) - fmaxf(a.y, b.y); iw = fmaxf(iw, 0.0f);
    float inter = ih * iw;
    float denom = (areaA + areaB - inter) + 1e-8f;
    return inter / denom;
}

// =============== fused select: histA -> histB -> compact -> rank -> mask -> nms ===============
__global__ __launch_bounds__(1024) void k_select(const uint4* __restrict__ sb4,
                                                 uint32_t* __restrict__ ha,
                                                 uint32_t* __restrict__ hb,
                                                 uint32_t* __restrict__ meta,
                                                 unsigned long long* __restrict__ cand,
                                                 uint32_t* __restrict__ topk,
                                                 const float4* __restrict__ boxes4,
                                                 float4* __restrict__ boxk,
                                                 unsigned long long* __restrict__ M,
                                                 const float* __restrict__ det,
                                                 float* __restrict__ out) {
    __shared__ __align__(16) uint32_t h[4096];
    __shared__ uint32_t wred[16];
    __shared__ uint32_t mr[2];
    __shared__ uint32_t wsum[16];
    __shared__ unsigned long long candS[CAP];    // 32 KB; 1 block/CU so LDS is plentiful
    __shared__ int keeplS[MAXB];
    __shared__ uint32_t topkS[TOPK];

    const int tid = threadIdx.x, wave = tid >> 6, lane = tid & 63;
    const int blk = blockIdx.x;
    uint32_t* bar = &meta[8];

    // ===== P1: level-A histogram (bits[31:20]) -> global ha (flush non-zero bins only) =====
    for (int i = tid; i < 4096; i += 1024) h[i] = 0;
    __syncthreads();
    for (int it = 0; it < ITH; it++) {
        int t4 = (it * NBH + blk) * 1024 + tid;
        bool v = t4 < N4;
        uint4 sv = v ? sb4[t4] : make_uint4(0, 0, 0, 0);
        agg_add(h, sv.x >> 20, v);
        agg_add(h, sv.y >> 20, v);
        agg_add(h, sv.z >> 20, v);
        agg_add(h, sv.w >> 20, v);
    }
    __syncthreads();
    for (int i = tid; i < 4096; i += 1024) { uint32_t v = h[i]; if (v) atomicAdd(&ha[i], v); }
    gridbar(bar, NBH * 1);

    // ===== P2: findthr(A) (redundant per block) + conditioned level-B histogram =====
    uint32_t c[4];
    {   // bins 4095-(tid*4+k) are 4 contiguous u32 -> one uint4 load, reversed
        uint4 q = ((const uint4*)ha)[1023 - tid];
        c[0] = q.w; c[1] = q.z; c[2] = q.y; c[3] = q.x;
    }
    findthr_core(c, wred, TOPK, mr);
    const uint32_t binA = mr[0], GA = mr[1];
    for (int i = tid; i < 4096; i += 1024) h[i] = 0;
    __syncthreads();
    for (int it = 0; it < ITH; it++) {
        int t4 = (it * NBH + blk) * 1024 + tid;
        if (t4 < N4) {
            uint4 sv = sb4[t4];
            if ((sv.x >> 20) == binA) atomicAdd(&h[(sv.x >> 8) & 0xFFFu], 1u);
            if ((sv.y >> 20) == binA) atomicAdd(&h[(sv.y >> 8) & 0xFFFu], 1u);
            if ((sv.z >> 20) == binA) atomicAdd(&h[(sv.z >> 8) & 0xFFFu], 1u);
            if ((sv.w >> 20) == binA) atomicAdd(&h[(sv.w >> 8) & 0xFFFu], 1u);
        }
    }
    __syncthreads();
    for (int i = tid; i < 4096; i += 1024) { uint32_t v = h[i]; if (v) atomicAdd(&hb[i], v); }
    gridbar(bar, NBH * 2);

    // ===== P3: findthr(B) + compact (2-phase, rank-stable, 1 global atomic per block) =====
    {
        uint4 q = ((const uint4*)hb)[1023 - tid];
        c[0] = q.w; c[1] = q.z; c[2] = q.y; c[3] = q.x;
    }
    findthr_core(c, wred, TOPK - GA, mr);
    const uint32_t T24 = (binA << 12) | mr[0];
    uint32_t cw = 0;
    for (int it = 0; it < ITH; it++) {
        int t4 = (it * NBH + blk) * 1024 + tid;
        bool v = t4 < N4;
        uint4 sv = v ? sb4[t4] : make_uint4(0, 0, 0, 0);
        uint32_t sl[4] = {sv.x, sv.y, sv.z, sv.w};
        #pragma unroll
        for (int s = 0; s < 4; s++) {
            bool m = v && ((sl[s] >> 8) >= T24);
            cw += (uint32_t)__popcll(__ballot(m));
        }
    }
    if (lane == 0) wsum[wave] = cw;
    __syncthreads();
    if (tid == 0) {
        uint32_t tot = 0;
        #pragma unroll
        for (int w = 0; w < 16; w++) tot += wsum[w];
        uint32_t base = atomicAdd(&meta[4], tot);
        uint32_t r = base;
        #pragma unroll
        for (int w = 0; w < 16; w++) { uint32_t c0 = wsum[w]; wsum[w] = r; r += c0; }
    }
    __syncthreads();
    uint32_t wbase = wsum[wave];
    for (int it = 0; it < ITH; it++) {
        int t4 = (it * NBH + blk) * 1024 + tid;
        bool v = t4 < N4;
        uint4 sv = v ? sb4[t4] : make_uint4(0, 0, 0, 0);
        uint32_t sl[4] = {sv.x, sv.y, sv.z, sv.w};
        #pragma unroll
        for (int s = 0; s < 4; s++) {
            uint32_t sb = sl[s];
            bool m = v && ((sb >> 8) >= T24);
            unsigned long long b = __ballot(m);
            if (m) {
                uint32_t p = wbase + (uint32_t)__popcll(b & ((1ull << lane) - 1ull));
                uint32_t idx = (uint32_t)(t4 * 4 + s);
                if (p < CAP) cand[p] = ((unsigned long long)sb << 32) | (uint32_t)(~idx);
            }
            wbase += (uint32_t)__popcll(b);
        }
    }
    gridbar(bar, NBH * 3);

    // ===== P4: exact rank — LDS-staged candidates, ONE WAVE per candidate =====
    // (lane-parallel: 64 lanes split the compare range; popcll(ballot) accumulate.
    //  Replaces the old wave-uniform j-loop that serialized C compares per thread.)
    uint32_t C = meta[4]; if (C > CAP) C = CAP;
    uint32_t Cpad = (C + 63u) & ~63u;
    for (uint32_t t = tid; t < Cpad; t += 1024) candS[t] = (t < C) ? cand[t] : 0ull;
    __syncthreads();
    for (uint32_t i = (uint32_t)(blk * 16 + wave); i < C; i += NBH * 16) {
        unsigned long long my = candS[i];        // LDS broadcast (free)
        uint32_t r = 0;
        for (uint32_t j0 = 0; j0 < Cpad; j0 += 64) {
            unsigned long long vj = candS[j0 + lane];   // contiguous b64: conflict-free
            r += (uint32_t)__popcll(__ballot(vj > my)); // 0-pad never > my (keys positive)
        }
        if (r < TOPK && lane == 0) {             // keys unique -> ranks unique, all 0..999 hit
            uint32_t idx = ~(uint32_t)(my & 0xFFFFFFFFull);
            if (idx < N_ANCH) { topk[r] = idx; boxk[r] = boxes4[idx]; }
        }
    }
    gridbar(bar, NBH * 4);

    // ===== P5: suppression bitmask M[i][w], boxes staged in LDS (reuse h: 16000B <= 16384B) =====
    float4* bks = (float4*)h;
    for (int i = tid; i < TOPK; i += 1024) bks[i] = boxk[i];
    __syncthreads();
    for (int gw = blk * 16 + wave; gw < TOPK * 16; gw += NBH * 16) {
        int i = gw >> 4, w = gw & 15;
        int j = w * 64 + lane;
        float4 bi = bks[i];
        float4 bj = bks[j < TOPK ? j : 0];
        bool ok = (j < TOPK) && (iou_f(bi, bj) > NMS_THR);
        unsigned long long m = __ballot(ok);
        if (lane == 0) M[i * 16 + w] = m;
    }
    gridbar(bar, NBH * 5);

    // ===== P6: block 0 — greedy scan (wave 0) + output gather (all waves) =====
    if (blk != 0) return;
    for (int i = tid; i < TOPK; i += 1024) topkS[i] = topk[i];
    if (tid < 64) {
        // ballot-reconstruction scan: row k of the 64x64 intra-chunk matrix equals
        // column k (IoU symmetry) = __ballot over lanes' own rows. kc chain is SALU.
        unsigned long long keptArr[16];
        #pragma unroll
        for (int cc = 0; cc < 16; cc++) {
            int i = cc * 64 + lane;
            unsigned long long pre = 0ull, Mic = 0ull;
            if (i < TOPK) {
                #pragma unroll
                for (int w = 0; w < cc; w++) pre |= M[i * 16 + w] & keptArr[w];
                Mic = M[i * 16 + cc];
            }
            unsigned long long pre_mask = __ballot(pre != 0ull);
            unsigned long long kc = 0ull;
            const int lim = (cc == 15) ? (TOPK - 960) : 64;
            for (int k = 0; k < lim; k++) {
                unsigned long long b = __ballot(((Mic >> k) & 1ull) != 0ull);
                bool sup = (((pre_mask >> k) & 1ull) != 0ull) || ((b & kc) != 0ull);
                kc |= sup ? 0ull : (1ull << k);
            }
            keptArr[cc] = kc;
        }
        uint32_t pfxw[16];
        uint32_t run = 0;
        #pragma unroll
        for (int w = 0; w < 16; w++) { pfxw[w] = run; run += (uint32_t)__popcll(keptArr[w]); }
        int total = (int)run; if (total > MAXB) total = MAXB;
        for (int r = total + lane; r < MAXB; r += 64) keeplS[r] = -1;
        #pragma unroll
        for (int w = 0; w < 16; w++) {
            int i = w * 64 + lane;
            if (i < TOPK) {
                unsigned long long kw = keptArr[w];
                if ((kw >> lane) & 1ull) {
                    uint32_t rank = pfxw[w] + (uint32_t)__popcll(kw & ((1ull << lane) - 1ull));
                    if (rank < MAXB) keeplS[rank] = i;
                }
            }
        }
    }
    __syncthreads();
    for (int t = tid; t < MAXB * DET_DIM; t += 1024) {
        int r = t / DET_DIM, col = t - r * DET_DIM;
        int pos = keeplS[r];
        float v = 0.0f;
        if (pos >= 0) v = det[(size_t)topkS[pos] * DET_DIM + col];
        out[t] = v;
    }
}

extern "C" void kernel_launch(void* const* d_in, const int* in_sizes, int n_in,
                              void* d_out, int out_size, void* d_ws, size_t ws_size,
                              hipStream_t stream) {
    const float4* boxes4 = (const float4*)d_in[0];
    const float4* cls4   = (const float4*)d_in[1];
    const float*  det    = (const float*)d_in[2];
    float* out = (float*)d_out;
    uint32_t* ws = (uint32_t*)d_ws;

    uint32_t* sbits = ws + OFF_SBITS;
    uint32_t* ha    = ws + OFF_HA;
    uint32_t* hb    = ws + OFF_HB;
    uint32_t* meta  = ws + OFF_META;
    unsigned long long* cand = (unsigned long long*)(ws + OFF_CAND);
    uint32_t* topk  = ws + OFF_TOPK;
    float4*   boxk  = (float4*)(ws + OFF_BOXK);
    unsigned long long* M = (unsigned long long*)(ws + OFF_MASK);

    k_scores<<<(N_ANCH + 63) / 64, 256, 0, stream>>>(cls4, sbits, ha, hb, meta);
    k_select<<<NBH, 1024, 0, stream>>>((const uint4*)sbits, ha, hb, meta, cand, topk,
                                       boxes4, boxk, M, det, out);
}

// Round 3
// 273.712 us; speedup vs baseline: 1.1366x; 1.0026x over previous
//
#include <hip/hip_runtime.h>
#include <stdint.h>

typedef unsigned long long u64;

#define N_ANCH   300000
#define N_CLS    80
#define DET_DIM  85
#define TOPK     1000
#define MAXB     300
#define NMS_THR  0.4f
#define CAP      4096
#define NBH      32                              // blocks for the fused select kernel
#define N4       (N_ANCH / 4)
#define ITH      ((N4 + NBH*1024 - 1) / (NBH*1024))

// ws layout (uint32 units)
#define OFF_SBITS   0          // 300000 u32
#define OFF_HA      300032     // 4096 u32 global hist A
#define OFF_HB      304128     // 4096 u32 global hist B
#define OFF_META    308224     // 64 u32: [4]=cand cnt [8]=grid barrier
#define OFF_CAND    308288     // 4096 u64 = 8192 u32 (byte %8==0)
#define OFF_TOPK    316480     // 1000 u32
#define OFF_BOXK    317480     // 1000 float4 (byte %16==0)
#define OFF_MASK    321480     // 16000 u64 (byte %8==0)
#define OFF_KEEPL   353480     // 300 u32

// ---------- L2-bypass (MALL-coherent) accessors: relaxed agent-scope atomics ----------
// Agent-scope atomics execute at the memory-side coherence point; relaxed ordering
// means NO buffer_inv/wbl2 fences are emitted — per-XCD L2s stay warm.
__device__ __forceinline__ uint32_t ld_b32(const uint32_t* p) {
    return __hip_atomic_load(p, __ATOMIC_RELAXED, __HIP_MEMORY_SCOPE_AGENT);
}
__device__ __forceinline__ u64 ld_b64(const u64* p) {
    return __hip_atomic_load(p, __ATOMIC_RELAXED, __HIP_MEMORY_SCOPE_AGENT);
}
__device__ __forceinline__ void st_b32(uint32_t* p, uint32_t v) {
    __hip_atomic_store(p, v, __ATOMIC_RELAXED, __HIP_MEMORY_SCOPE_AGENT);
}
__device__ __forceinline__ void st_b64(u64* p, u64 v) {
    __hip_atomic_store(p, v, __ATOMIC_RELAXED, __HIP_MEMORY_SCOPE_AGENT);
}
__device__ __forceinline__ void st_f4(float4* p, float4 v) {
    union { float4 f; u64 u[2]; } cv; cv.f = v;
    u64* q = (u64*)p;
    st_b64(q, cv.u[0]); st_b64(q + 1, cv.u[1]);
}
__device__ __forceinline__ float4 ld_f4(const float4* p) {
    union { float4 f; u64 u[2]; } cv;
    const u64* q = (const u64*)p;
    cv.u[0] = ld_b64(q); cv.u[1] = ld_b64(q + 1);
    return cv.f;
}

// ---------- fence-free grid barrier (NBH co-resident blocks, monotone counter) ----------
// Release: __syncthreads() drains each thread's vmcnt before s_barrier (HIP semantics),
// so all bypass stores are at the MALL before thread0's RMW. Acquire: spin with relaxed
// agent load (bypasses stale L2); subsequent data reads are bypass too -> coherent.
__device__ __forceinline__ void gb_arrive(uint32_t* bar) {
    __syncthreads();
    if (threadIdx.x == 0)
        __hip_atomic_fetch_add(bar, 1u, __ATOMIC_RELAXED, __HIP_MEMORY_SCOPE_AGENT);
}
__device__ __forceinline__ void gb_wait(uint32_t* bar, uint32_t target) {
    if (threadIdx.x == 0) {
        while (__hip_atomic_load(bar, __ATOMIC_RELAXED, __HIP_MEMORY_SCOPE_AGENT) < target)
            __builtin_amdgcn_s_sleep(1);
    }
    __syncthreads();
}

// ---------------- scores = max over 80 classes (pure BW pass) ----------------
__global__ __launch_bounds__(256) void k_scores(const float4* __restrict__ cls4,
                                                uint32_t* __restrict__ sbits,
                                                uint32_t* __restrict__ ha,
                                                uint32_t* __restrict__ hb,
                                                uint32_t* __restrict__ meta) {
    int tid = threadIdx.x;
    if (blockIdx.x == 0) {                       // zero cross-block state (ws poisoned)
        if (tid == 0) { meta[4] = 0; meta[8] = 0; }
        for (int i = tid; i < 4096; i += 256) { ha[i] = 0; hb[i] = 0; }
    }
    int wave = tid >> 6, lane = tid & 63, g = lane >> 2, q = lane & 3;
    int row = blockIdx.x * 64 + wave * 16 + g;
    if (row >= N_ANCH) return;
    const float4* rp = cls4 + (size_t)row * 20;  // 80 floats = 20 float4
    float m = -1.0f;
    #pragma unroll
    for (int k = 0; k < 5; k++) {
        float4 v = rp[q + k * 4];
        m = fmaxf(m, fmaxf(fmaxf(v.x, v.y), fmaxf(v.z, v.w)));
    }
    m = fmaxf(m, __shfl_xor(m, 1));
    m = fmaxf(m, __shfl_xor(m, 2));
    if (q == 0) sbits[row] = __float_as_uint(m); // scores >= 0: bit order == value order
}

// ballot-aggregated LDS histogram add (level-A distribution is degenerate:
// ~99% of maxes land in a handful of bits[31:20] bins).
__device__ __forceinline__ void agg_add(uint32_t* h, uint32_t bin, bool valid) {
    int lane = threadIdx.x & 63;
    bool done = !valid;
    while (true) {
        unsigned long long rem = __ballot(!done);
        if (rem == 0ull) break;
        int leader = __ffsll((long long)rem) - 1;
        uint32_t lbin = __shfl(bin, leader);
        bool mine = (!done) && (bin == lbin);
        unsigned long long grp = __ballot(mine);
        if (lane == leader) atomicAdd(&h[lbin], (uint32_t)__popcll(grp));
        done = done || mine;
    }
}

// block-wide (1024 thr) threshold find via shfl wave-scan:
// per-thread counts c[k] for bins 4095-(tid*4+k); find bin where descending-suffix
// count crosses K. res[0]=bin, res[1]=count strictly above. Ends synced.
__device__ __forceinline__ void findthr_core(const uint32_t c[4], uint32_t* wred,
                                             uint32_t K, uint32_t* res) {
    int tid = threadIdx.x, lane = tid & 63, wave = tid >> 6;
    uint32_t s = c[0] + c[1] + c[2] + c[3];
    uint32_t x = s;
    #pragma unroll
    for (int off = 1; off < 64; off <<= 1) {
        uint32_t v = __shfl_up(x, off);
        if (lane >= off) x += v;
    }
    if (lane == 63) wred[wave] = x;
    __syncthreads();
    if (wave == 0) {
        uint32_t w = (lane < 16) ? wred[lane] : 0u;
        #pragma unroll
        for (int off = 1; off < 16; off <<= 1) {
            uint32_t v = __shfl_up(w, off);
            if (lane >= off) w += v;
        }
        if (lane < 16) wred[lane] = w;
    }
    __syncthreads();
    uint32_t base = (wave == 0) ? 0u : wred[wave - 1];
    uint32_t incl = base + x, excl = incl - s;
    if (excl < K && incl >= K) {                 // exactly one thread matches
        uint32_t run = excl;
        #pragma unroll
        for (int k = 0; k < 4; k++) {
            uint32_t nr = run + c[k];
            if (run < K && nr >= K) { res[0] = 4095 - (tid * 4 + k); res[1] = run; }
            run = nr;
        }
    }
    __syncthreads();
}

// MS bank-swizzle: row stride 16 u64 = 128 B puts every lane in the same bank;
// rotating the word index by the row spreads 16 lanes across 16 bank-pairs.
#define MSW(i, w) ((i) * 16 + (((w) + (i)) & 15))

// =============== fused select: histA -> histB -> compact -> rank -> mask -> nms ===============
__global__ __launch_bounds__(1024) void k_select(const uint4* __restrict__ sb4,
                                                 uint32_t* __restrict__ ha,
                                                 uint32_t* __restrict__ hb,
                                                 uint32_t* __restrict__ meta,
                                                 u64* __restrict__ cand,
                                                 uint32_t* __restrict__ topk,
                                                 const float4* __restrict__ boxes4,
                                                 float4* __restrict__ boxk,
                                                 u64* __restrict__ M,
                                                 uint32_t* __restrict__ keepl,
                                                 const float* __restrict__ det,
                                                 float* __restrict__ out) {
    // one big LDS arena, phase-aliased:
    //  P1-P3: h[4096] u32 (16 KB) | P4: candS[4096] u64 (32 KB)
    //  P5: bks[1000] f4 (16 KB) + areaS[1000] f32 | P6 (blk0): MS[16000] u64 (128 KB)
    __shared__ __align__(16) u64 big[16000];
    __shared__ uint32_t wred[16];
    __shared__ uint32_t mr[2];
    __shared__ uint32_t kidS[MAXB];

    const int tid = threadIdx.x, wave = tid >> 6, lane = tid & 63;
    const int blk = blockIdx.x;
    uint32_t* bar = &meta[8];
    uint32_t* h = (uint32_t*)big;

    // ===== P1: partitioned level-A histogram (bits[31:20]) -> global ha =====
    for (int i = tid; i < 4096; i += 1024) h[i] = 0;
    __syncthreads();
    for (int it = 0; it < ITH; it++) {
        int t4 = (it * NBH + blk) * 1024 + tid;
        bool v = t4 < N4;
        uint4 sv = v ? sb4[t4] : make_uint4(0, 0, 0, 0);
        agg_add(h, sv.x >> 20, v);
        agg_add(h, sv.y >> 20, v);
        agg_add(h, sv.z >> 20, v);
        agg_add(h, sv.w >> 20, v);
    }
    __syncthreads();
    for (int i = tid; i < 4096; i += 1024) { uint32_t v = h[i]; if (v) atomicAdd(&ha[i], v); }
    gb_arrive(bar); gb_wait(bar, NBH * 1);

    // ===== P2: findthr(A) (redundant per block, bypass reads) + conditioned B-hist =====
    uint32_t c[4];
    {
        uint32_t* base = ha + 4u * (1023u - (uint32_t)tid);
        c[0] = ld_b32(base + 3); c[1] = ld_b32(base + 2);
        c[2] = ld_b32(base + 1); c[3] = ld_b32(base + 0);
    }
    findthr_core(c, wred, TOPK, mr);
    const uint32_t binA = mr[0], GA = mr[1];
    for (int i = tid; i < 4096; i += 1024) h[i] = 0;
    __syncthreads();
    for (int it = 0; it < ITH; it++) {
        int t4 = (it * NBH + blk) * 1024 + tid;
        if (t4 < N4) {
            uint4 sv = sb4[t4];
            if ((sv.x >> 20) == binA) atomicAdd(&h[(sv.x >> 8) & 0xFFFu], 1u);
            if ((sv.y >> 20) == binA) atomicAdd(&h[(sv.y >> 8) & 0xFFFu], 1u);
            if ((sv.z >> 20) == binA) atomicAdd(&h[(sv.z >> 8) & 0xFFFu], 1u);
            if ((sv.w >> 20) == binA) atomicAdd(&h[(sv.w >> 8) & 0xFFFu], 1u);
        }
    }
    __syncthreads();
    for (int i = tid; i < 4096; i += 1024) { uint32_t v = h[i]; if (v) atomicAdd(&hb[i], v); }
    gb_arrive(bar); gb_wait(bar, NBH * 2);

    // ===== P3: findthr(B) + single-pass compact (per-wave leader atomic; order irrelevant) =====
    {
        uint32_t* base = hb + 4u * (1023u - (uint32_t)tid);
        c[0] = ld_b32(base + 3); c[1] = ld_b32(base + 2);
        c[2] = ld_b32(base + 1); c[3] = ld_b32(base + 0);
    }
    findthr_core(c, wred, TOPK - GA, mr);
    const uint32_t T24 = (binA << 12) | mr[0];
    for (int it = 0; it < ITH; it++) {
        int t4 = (it * NBH + blk) * 1024 + tid;
        bool v = t4 < N4;
        uint4 sv = v ? sb4[t4] : make_uint4(0, 0, 0, 0);
        uint32_t sl[4] = {sv.x, sv.y, sv.z, sv.w};
        #pragma unroll
        for (int s = 0; s < 4; s++) {
            uint32_t sb = sl[s];
            bool m = v && ((sb >> 8) >= T24);
            unsigned long long b = __ballot(m);
            if (b) {                              // wave-uniform
                int leader = __ffsll((long long)b) - 1;
                uint32_t base2 = 0;
                if (lane == leader) base2 = atomicAdd(&meta[4], (uint32_t)__popcll(b));
                base2 = __shfl(base2, leader);
                if (m) {
                    uint32_t p = base2 + (uint32_t)__popcll(b & ((1ull << lane) - 1ull));
                    uint32_t idx = (uint32_t)(t4 * 4 + s);
                    if (p < CAP) st_b64(&cand[p], ((u64)sb << 32) | (uint32_t)(~idx));
                }
            }
        }
    }
    gb_arrive(bar); gb_wait(bar, NBH * 3);

    // ===== P4: exact rank — LDS-staged candidates, one wave per candidate =====
    u64* candS = big;
    uint32_t C = ld_b32(&meta[4]); if (C > CAP) C = CAP;
    uint32_t Cpad = (C + 63u) & ~63u;
    for (uint32_t t = tid; t < Cpad; t += 1024) candS[t] = (t < C) ? ld_b64(&cand[t]) : 0ull;
    __syncthreads();
    for (uint32_t i = (uint32_t)(blk * 16 + wave); i < C; i += NBH * 16) {
        u64 my = candS[i];
        uint32_t r = 0;
        for (uint32_t j0 = 0; j0 < Cpad; j0 += 64)
            r += (uint32_t)__popcll(__ballot(candS[j0 + lane] > my));
        if (r < TOPK && lane == 0) {              // keys unique -> all ranks 0..999 hit once
            uint32_t idx = ~(uint32_t)(my & 0xFFFFFFFFull);
            if (idx < N_ANCH) { st_b32(&topk[r], idx); st_f4(&boxk[r], boxes4[idx]); }
        }
    }
    gb_arrive(bar); gb_wait(bar, NBH * 4);

    // ===== P5: suppression bitmask M[i][w] (spread), boxes + areas staged in LDS =====
    float4* bks  = (float4*)big;                  // 16000 B
    float* areaS = (float*)((char*)big + 16000);  // 4000 B
    for (int i = tid; i < TOPK; i += 1024) {
        float4 b = ld_f4(&boxk[i]);
        bks[i] = b;
        {
            #pragma clang fp contract(off)
            areaS[i] = (b.z - b.x) * (b.w - b.y);
        }
    }
    __syncthreads();
    for (int gw = blk * 16 + wave; gw < TOPK * 16; gw += NBH * 16) {
        int i = gw >> 4, w = gw & 15;
        int j = w * 64 + lane, jc = j < TOPK ? j : 0;
        float4 bi = bks[i], bj = bks[jc];
        bool ok;
        {
            #pragma clang fp contract(off)
            float ih = fminf(bi.z, bj.z) - fmaxf(bi.x, bj.x); ih = fmaxf(ih, 0.0f);
            float iw = fminf(bi.w, bj.w) - fmaxf(bi.y, bj.y); iw = fmaxf(iw, 0.0f);
            float inter = ih * iw;
            float denom = (areaS[i] + areaS[jc] - inter) + 1e-8f;
            ok = (j < TOPK) && (inter / denom > NMS_THR);
        }
        unsigned long long m = __ballot(ok);
        if (lane == 0) st_b64(&M[i * 16 + w], m);
    }
    gb_arrive(bar);                               // barrier 5: blk!=0 arrive-only

    // ===== P6: block 0 — stage M to LDS (swizzled), greedy scan, publish kept anchors =====
    if (blk == 0) {
        gb_wait(bar, NBH * 5);
        u64* MS = big;
        for (int t = tid; t < TOPK * 16; t += 1024) {
            int i = t >> 4, w = t & 15;
            MS[MSW(i, w)] = ld_b64(&M[t]);
        }
        __syncthreads();
        if (tid < 64) {
            // ballot-reconstruction scan: row k of the 64x64 intra-chunk matrix equals
            // column k (IoU symmetry) = __ballot over lanes' own rows. kc chain is SALU.
            u64 keptArr[16];
            #pragma unroll
            for (int cc = 0; cc < 16; cc++) {
                int i = cc * 64 + lane;
                u64 pre = 0ull, Mic = 0ull;
                if (i < TOPK) {
                    #pragma unroll
                    for (int w = 0; w < cc; w++) pre |= MS[MSW(i, w)] & keptArr[w];
                    Mic = MS[MSW(i, cc)];
                }
                unsigned long long pre_mask = __ballot(pre != 0ull);
                u64 kc = 0ull;
                const int lim = (cc == 15) ? (TOPK - 960) : 64;
                for (int k = 0; k < lim; k++) {
                    unsigned long long b = __ballot(((Mic >> k) & 1ull) != 0ull);
                    bool sup = (((pre_mask >> k) & 1ull) != 0ull) || ((b & kc) != 0ull);
                    kc |= sup ? 0ull : (1ull << k);
                }
                keptArr[cc] = kc;
            }
            uint32_t pfxw[16];
            uint32_t run = 0;
            #pragma unroll
            for (int w = 0; w < 16; w++) { pfxw[w] = run; run += (uint32_t)__popcll(keptArr[w]); }
            int total = (int)run; if (total > MAXB) total = MAXB;
            for (int r = total + lane; r < MAXB; r += 64) st_b32(&keepl[r], 0xFFFFFFFFu);
            #pragma unroll
            for (int w = 0; w < 16; w++) {
                int i = w * 64 + lane;
                if (i < TOPK) {
                    u64 kw = keptArr[w];
                    if ((kw >> lane) & 1ull) {
                        uint32_t rank = pfxw[w] + (uint32_t)__popcll(kw & ((1ull << lane) - 1ull));
                        if (rank < MAXB) st_b32(&keepl[rank], ld_b32(&topk[i]));  // anchor id
                    }
                }
            }
        }
    }
    gb_arrive(bar); gb_wait(bar, NBH * 6);

    // ===== P7: all blocks gather output rows (300 x 85) in one parallel pass =====
    if (tid < MAXB) kidS[tid] = ld_b32(&keepl[tid]);
    __syncthreads();
    int t = blk * 1024 + tid;
    if (t < MAXB * DET_DIM) {
        int r = t / DET_DIM, col = t - r * DET_DIM;
        uint32_t src = kidS[r];
        float v = 0.0f;
        if (src < N_ANCH) v = det[(size_t)src * DET_DIM + col];
        out[t] = v;
    }
}

extern "C" void kernel_launch(void* const* d_in, const int* in_sizes, int n_in,
                              void* d_out, int out_size, void* d_ws, size_t ws_size,
                              hipStream_t stream) {
    const float4* boxes4 = (const float4*)d_in[0];
    const float4* cls4   = (const float4*)d_in[1];
    const float*  det    = (const float*)d_in[2];
    float* out = (float*)d_out;
    uint32_t* ws = (uint32_t*)d_ws;

    uint32_t* sbits = ws + OFF_SBITS;
    uint32_t* ha    = ws + OFF_HA;
    uint32_t* hb    = ws + OFF_HB;
    uint32_t* meta  = ws + OFF_META;
    u64*      cand  = (u64*)(ws + OFF_CAND);
    uint32_t* topk  = ws + OFF_TOPK;
    float4*   boxk  = (float4*)(ws + OFF_BOXK);
    u64*      M     = (u64*)(ws + OFF_MASK);
    uint32_t* keepl = ws + OFF_KEEPL;

    k_scores<<<(N_ANCH + 63) / 64, 256, 0, stream>>>(cls4, sbits, ha, hb, meta);
    k_select<<<NBH, 1024, 0, stream>>>((const uint4*)sbits, ha, hb, meta, cand, topk,
                                       boxes4, boxk, M, keepl, det, out);
}